// Round 1
// baseline (349.000 us; speedup 1.0000x reference)
//
#include <hip/hip_runtime.h>
#include <math.h>

// Refactoring notes:
//  Wc = W_msg[:,:,0,4]  (256x256)
//  Pass1 (fwd):  y[0]=x[:,:,:,0]; y[k]=x[:,:,:,k]+relu(Wc@y[k-1]); out1[...,w]=y[24-w]
//  t1 = relu(BN(out1))
//  Pass2 (rev) on t1 == z'[0]=f(y[0]); z'[k]=f(y[k])+relu(Wc@z'[k-1]);  t2[...,w]=f(z'[24-w])
//  where f(v)=relu(v*inv+add), inv=gamma/sqrt(var+eps), add=beta-mean*inv
//  Tail is linear: fold W_conv into conv weights, fold W_conv2 + w-padding:
//    Weff[c,dh,dw] = sum_o cw1[o]*W_up2[o,c,dh,dw]
//    A[c,dh,j]     = sum_dw Weff[c,dh,dw]*cw2[j+1-dw]   (valid j+1-dw in [0,25))
//    S[b,hi,dh]    = sum_{c,j} A[c,dh,j]*t2[b,c,hi,j]        (accumulated inside K2)
//    P[b,h'] (h'<512) = sum_dh lerp_{255/511}(S[b,:,dh] at h'+dh-1), zero-padded in h'
//    out[b,H] = sigmoid( lerp_{1023/2047}( lerp_{511/1023}( P ) ) )

#define NC 8

__device__ __forceinline__ float relu_(float v) { return fmaxf(v, 0.f); }

__global__ __launch_bounds__(64) void k0_precompute(
    const float* __restrict__ Wmsg, const float* __restrict__ gamma,
    const float* __restrict__ beta, const float* __restrict__ mean,
    const float* __restrict__ var, const float* __restrict__ Wup2,
    const float* __restrict__ Wconv, const float* __restrict__ Wconv2,
    float* __restrict__ WcT, float* __restrict__ A, float* __restrict__ bnp)
{
  const int c = blockIdx.x;      // 0..255
  const int lane = threadIdx.x;  // 0..63

  // WcT[c][o] = Wc[o][c] (coalesced-over-o loads in K2)
  for (int o = lane; o < 256; o += 64)
    WcT[c * 256 + o] = Wmsg[(o * 256 + c) * 9 + 4];

  // BN affine params
  const int gtid = c * 64 + lane;
  if (gtid < 256) {
    float inv = gamma[gtid] / sqrtf(var[gtid] + 1e-5f);
    bnp[gtid] = inv;
    bnp[256 + gtid] = beta[gtid] - mean[gtid] * inv;
  }

  // Weff[c][dh][dw] = sum_o cw1[o]*W_up2[o,c,dh,dw]
  float wacc[9];
#pragma unroll
  for (int q = 0; q < 9; ++q) wacc[q] = 0.f;
  for (int o = lane; o < 256; o += 64) {
    float cw = Wconv[o];
    const float* wp = Wup2 + (size_t)(o * 256 + c) * 9;
#pragma unroll
    for (int q = 0; q < 9; ++q) wacc[q] += cw * wp[q];
  }
#pragma unroll
  for (int q = 0; q < 9; ++q) {
    float v = wacc[q];
    v += __shfl_xor(v, 32, 64);
    v += __shfl_xor(v, 16, 64);
    v += __shfl_xor(v, 8, 64);
    v += __shfl_xor(v, 4, 64);
    v += __shfl_xor(v, 2, 64);
    v += __shfl_xor(v, 1, 64);
    wacc[q] = v;
  }
  if (lane == 0) {
    for (int dh = 0; dh < 3; ++dh)
      for (int j = 0; j < 25; ++j) {
        float a = 0.f;
        for (int dw = 0; dw < 3; ++dw) {
          int w = j + 1 - dw;
          if (w >= 0 && w < 25) a += wacc[dh * 3 + dw] * Wconv2[w];
        }
        A[(dh * 25 + j) * 256 + c] = a;
      }
  }
}

// x0T[((b*256+h)*25+w)*256+c] = x0[((b*256+c)*256+h)*25+w]
__global__ __launch_bounds__(256) void k1_transpose(
    const float* __restrict__ in, float* __restrict__ out)
{
  __shared__ float tile[32][33];
  const int nt = blockIdx.x;            // 0..199  (n = h*25+w, 6400 = 200*32)
  const int ct = blockIdx.y;            // 0..7    (c, 256 = 8*32)
  const int b = blockIdx.z;             // 0..7
  const int tx = threadIdx.x & 31, ty = threadIdx.x >> 5;  // 32 x 8
  const int n = nt * 32 + tx;
#pragma unroll
  for (int r = 0; r < 4; ++r) {
    int c = ct * 32 + ty + r * 8;
    tile[ty + r * 8][tx] = in[(size_t)(b * 256 + c) * 6400 + n];
  }
  __syncthreads();
  const int c2 = ct * 32 + tx;
#pragma unroll
  for (int r = 0; r < 4; ++r) {
    int n2 = nt * 32 + ty + r * 8;
    out[(size_t)(b * 6400 + n2) * 256 + c2] = tile[tx][ty + r * 8];
  }
}

// Fused dual recurrence + BN/ReLU + A-weighted reduction.
// Block = 256 threads (thread = channel o), handles NC consecutive (b,h) columns.
template <bool TR>
__global__ __launch_bounds__(256) void k2_scnn(
    const float* __restrict__ X,    // TR ? x0T [col][w][c] : x0 [b][c][h][w]
    const float* __restrict__ WcT,  // [c][o]
    const float* __restrict__ A,    // [(dh*25+j)*256+c]
    const float* __restrict__ bnp,  // inv[256], add[256]
    float* __restrict__ S)          // [col*3+dh]
{
  __shared__ float ly[256 * NC];
  __shared__ float lz[256 * NC];
  __shared__ float red[4 * NC * 3];
  const int o = threadIdx.x;
  const int col0 = blockIdx.x * NC;  // col = b*256+h; NC divides 256 so same b
  const float inv = bnp[o], add = bnp[256 + o];

  float yv[NC], zv[NC], sA0[NC], sA1[NC], sA2[NC];
#pragma unroll
  for (int n = 0; n < NC; ++n) { sA0[n] = 0.f; sA1[n] = 0.f; sA2[n] = 0.f; }

  auto loadx = [&](int n, int w) -> float {
    if (TR) {
      return X[(size_t)(col0 + n) * 6400 + w * 256 + o];
    } else {
      int b = col0 >> 8, h = (col0 & 255) + n;
      return X[((size_t)(b * 256 + o) * 256 + h) * 25 + w];
    }
  };

  // k = 0
#pragma unroll
  for (int n = 0; n < NC; ++n) {
    yv[n] = loadx(n, 0);
    zv[n] = relu_(yv[n] * inv + add);
  }
  {
    const int w = 24;
    float a0 = A[(0 * 25 + w) * 256 + o];
    float a1 = A[(1 * 25 + w) * 256 + o];
    float a2 = A[(2 * 25 + w) * 256 + o];
#pragma unroll
    for (int n = 0; n < NC; ++n) {
      float t2c = relu_(zv[n] * inv + add);
      sA0[n] += a0 * t2c; sA1[n] += a1 * t2c; sA2[n] += a2 * t2c;
    }
  }

  for (int k = 1; k < 25; ++k) {
    float4* lyw = (float4*)ly;
    float4* lzw = (float4*)lz;
    lyw[o * 2]     = make_float4(yv[0], yv[1], yv[2], yv[3]);
    lyw[o * 2 + 1] = make_float4(yv[4], yv[5], yv[6], yv[7]);
    lzw[o * 2]     = make_float4(zv[0], zv[1], zv[2], zv[3]);
    lzw[o * 2 + 1] = make_float4(zv[4], zv[5], zv[6], zv[7]);
    __syncthreads();

    float ay[NC], az[NC];
#pragma unroll
    for (int n = 0; n < NC; ++n) { ay[n] = 0.f; az[n] = 0.f; }
    const float4* lyv = (const float4*)ly;
    const float4* lzv = (const float4*)lz;
#pragma unroll 4
    for (int c = 0; c < 256; ++c) {
      float wv = WcT[c * 256 + o];
      float4 ya = lyv[2 * c], yb = lyv[2 * c + 1];
      float4 za = lzv[2 * c], zb = lzv[2 * c + 1];
      ay[0] = fmaf(wv, ya.x, ay[0]); ay[1] = fmaf(wv, ya.y, ay[1]);
      ay[2] = fmaf(wv, ya.z, ay[2]); ay[3] = fmaf(wv, ya.w, ay[3]);
      ay[4] = fmaf(wv, yb.x, ay[4]); ay[5] = fmaf(wv, yb.y, ay[5]);
      ay[6] = fmaf(wv, yb.z, ay[6]); ay[7] = fmaf(wv, yb.w, ay[7]);
      az[0] = fmaf(wv, za.x, az[0]); az[1] = fmaf(wv, za.y, az[1]);
      az[2] = fmaf(wv, za.z, az[2]); az[3] = fmaf(wv, za.w, az[3]);
      az[4] = fmaf(wv, zb.x, az[4]); az[5] = fmaf(wv, zb.y, az[5]);
      az[6] = fmaf(wv, zb.z, az[6]); az[7] = fmaf(wv, zb.w, az[7]);
    }

    const int w = 24 - k;
    float a0 = A[(0 * 25 + w) * 256 + o];
    float a1 = A[(1 * 25 + w) * 256 + o];
    float a2 = A[(2 * 25 + w) * 256 + o];
#pragma unroll
    for (int n = 0; n < NC; ++n) {
      float ynew = loadx(n, k) + relu_(ay[n]);
      float t1c = relu_(ynew * inv + add);
      float znew = t1c + relu_(az[n]);
      float t2c = relu_(znew * inv + add);
      sA0[n] += a0 * t2c; sA1[n] += a1 * t2c; sA2[n] += a2 * t2c;
      yv[n] = ynew;
      zv[n] = znew;
    }
    __syncthreads();
  }

  // Reduce sA over threads (channel axis) -> S[col][dh]
  const int lane = o & 63, wid = o >> 6;
#pragma unroll
  for (int n = 0; n < NC; ++n) {
#pragma unroll
    for (int dh = 0; dh < 3; ++dh) {
      float v = (dh == 0) ? sA0[n] : (dh == 1 ? sA1[n] : sA2[n]);
      v += __shfl_xor(v, 32, 64);
      v += __shfl_xor(v, 16, 64);
      v += __shfl_xor(v, 8, 64);
      v += __shfl_xor(v, 4, 64);
      v += __shfl_xor(v, 2, 64);
      v += __shfl_xor(v, 1, 64);
      if (lane == 0) red[wid * (NC * 3) + n * 3 + dh] = v;
    }
  }
  __syncthreads();
  if (o < NC * 3) {
    float v = red[o] + red[NC * 3 + o] + red[2 * NC * 3 + o] + red[3 * NC * 3 + o];
    int n = o / 3, dh = o % 3;
    S[(size_t)(col0 + n) * 3 + dh] = v;
  }
}

// P[b][h'] for h' in [0,512): conv-h fold + first upsample (256->512)
__global__ __launch_bounds__(256) void k3_outpre(
    const float* __restrict__ S, float* __restrict__ P)
{
  int idx = blockIdx.x * blockDim.x + threadIdx.x;
  if (idx >= 8 * 512) return;
  int b = idx >> 9, h = idx & 511;
  float acc = 0.f;
#pragma unroll
  for (int dh = 0; dh < 3; ++dh) {
    int hh = h + dh - 1;
    if (hh < 0 || hh >= 512) continue;
    float pos = hh * (255.0f / 511.0f);
    int i0 = (int)floorf(pos);
    int i1 = min(i0 + 1, 255);
    float t = pos - (float)i0;
    acc += (1.f - t) * S[(size_t)(b * 256 + i0) * 3 + dh]
         + t * S[(size_t)(b * 256 + i1) * 3 + dh];
  }
  P[idx] = acc;
}

// Final: two more upsamples (512->1024->2048) + sigmoid
__global__ __launch_bounds__(256) void k4_final(
    const float* __restrict__ P, float* __restrict__ out)
{
  int idx = blockIdx.x * blockDim.x + threadIdx.x;
  if (idx >= 8 * 2048) return;
  int b = idx >> 11, H = idx & 2047;
  const float* Pb = P + b * 512;

  float pos3 = H * (1023.0f / 2047.0f);
  int i3 = (int)floorf(pos3);
  int i3b = min(i3 + 1, 1023);
  float t3 = pos3 - (float)i3;

  float v[2];
#pragma unroll
  for (int q = 0; q < 2; ++q) {
    int i = q ? i3b : i3;
    float pos2 = i * (511.0f / 1023.0f);
    int i2 = (int)floorf(pos2);
    int i2b = min(i2 + 1, 511);
    float t2 = pos2 - (float)i2;
    v[q] = (1.f - t2) * Pb[i2] + t2 * Pb[i2b];
  }
  float val = (1.f - t3) * v[0] + t3 * v[1];
  out[idx] = 1.f / (1.f + expf(-val));
}

extern "C" void kernel_launch(void* const* d_in, const int* in_sizes, int n_in,
                              void* d_out, int out_size, void* d_ws, size_t ws_size,
                              hipStream_t stream) {
  (void)in_sizes; (void)n_in; (void)out_size;
  const float* p2r    = (const float*)d_in[0];
  const float* Wmsg   = (const float*)d_in[1];
  const float* gamma  = (const float*)d_in[2];
  const float* beta   = (const float*)d_in[3];
  const float* mean   = (const float*)d_in[4];
  const float* var    = (const float*)d_in[5];
  const float* Wup2   = (const float*)d_in[6];
  const float* Wconv  = (const float*)d_in[7];
  const float* Wconv2 = (const float*)d_in[8];
  float* out = (float*)d_out;

  float* ws = (float*)d_ws;
  const size_t X0T_ELEMS = (size_t)8 * 256 * 25 * 256;  // 13,107,200 floats
  const size_t SMALL_ELEMS = 65536 + 19200 + 512 + 6144 + 4096 + 64;
  bool use_tr = ws_size >= (X0T_ELEMS + SMALL_ELEMS) * sizeof(float);

  size_t off = 0;
  float* x0T = nullptr;
  if (use_tr) { x0T = ws; off += X0T_ELEMS; }
  float* WcT = ws + off;  off += 65536;
  float* Abuf = ws + off; off += 19200;
  float* bnp = ws + off;  off += 512;
  float* S = ws + off;    off += 6144;
  float* P = ws + off;    off += 4096;

  k0_precompute<<<256, 64, 0, stream>>>(Wmsg, gamma, beta, mean, var, Wup2,
                                        Wconv, Wconv2, WcT, Abuf, bnp);
  if (use_tr) {
    dim3 tg(200, 8, 8);
    k1_transpose<<<tg, 256, 0, stream>>>(p2r, x0T);
    k2_scnn<true><<<256, 256, 0, stream>>>(x0T, WcT, Abuf, bnp, S);
  } else {
    k2_scnn<false><<<256, 256, 0, stream>>>(p2r, WcT, Abuf, bnp, S);
  }
  k3_outpre<<<16, 256, 0, stream>>>(S, P);
  k4_final<<<64, 256, 0, stream>>>(P, out);
}

// Round 2
// 82.199 us; speedup vs baseline: 4.2458x; 4.2458x over previous
//
#include <hip/hip_runtime.h>
#include <math.h>

// Algebraic refactor (verified round 1, absmax 0.0):
//  y[0]=x[...,0]; y[k]=x[...,k]+relu(Wc@y[k-1])
//  z[0]=f(y[0]);  z[k]=f(y[k])+relu(Wc@z[k-1]),  f(v)=relu(v*inv+add)
//  S[col][dh] = sum_{o,k} A[dh][24-k][o] * f(z[k])[o][col]
//  tail: lerp chains + sigmoid (k3,k4)
// Round 2: k2 rebuilt on MFMA (16x16x32 bf16). Per block: 8 columns,
//  N=16 (8 y + 8 z), M=256, K=256 per step. Wc in registers as bf16
//  A-fragments; y/z state double-buffered in swizzled LDS as B-fragments.

#define NC 8

typedef __attribute__((ext_vector_type(8))) short bf16x8;
typedef __attribute__((ext_vector_type(4))) float f32x4;

__device__ __forceinline__ float relu_(float v) { return fmaxf(v, 0.f); }

__device__ __forceinline__ short f2bf(float f) {
  union { float f; unsigned u; } v; v.f = f;
  unsigned r = (v.u + 0x7fffu + ((v.u >> 16) & 1u)) >> 16;
  return (short)r;
}

__global__ __launch_bounds__(64) void k0_precompute(
    const float* __restrict__ Wmsg, const float* __restrict__ gamma,
    const float* __restrict__ beta, const float* __restrict__ mean,
    const float* __restrict__ var, const float* __restrict__ Wup2,
    const float* __restrict__ Wconv, const float* __restrict__ Wconv2,
    float* __restrict__ WcT, short* __restrict__ WcA,
    float* __restrict__ A, float* __restrict__ bnp)
{
  const int c = blockIdx.x;      // 0..255
  const int lane = threadIdx.x;  // 0..63

  // WcT[c][o] = Wc[o][c] (for fallback VALU kernel)
  // WcA[o][c] = bf16(Wc[o][c]) (MFMA A operand, row-major [M=o][K=c])
  for (int o = lane; o < 256; o += 64) {
    float w = Wmsg[(o * 256 + c) * 9 + 4];
    WcT[c * 256 + o] = w;
    WcA[o * 256 + c] = f2bf(w);
  }

  const int gtid = c * 64 + lane;
  if (gtid < 256) {
    float inv = gamma[gtid] / sqrtf(var[gtid] + 1e-5f);
    bnp[gtid] = inv;
    bnp[256 + gtid] = beta[gtid] - mean[gtid] * inv;
  }

  float wacc[9];
#pragma unroll
  for (int q = 0; q < 9; ++q) wacc[q] = 0.f;
  for (int o = lane; o < 256; o += 64) {
    float cw = Wconv[o];
    const float* wp = Wup2 + (size_t)(o * 256 + c) * 9;
#pragma unroll
    for (int q = 0; q < 9; ++q) wacc[q] += cw * wp[q];
  }
#pragma unroll
  for (int q = 0; q < 9; ++q) {
    float v = wacc[q];
    v += __shfl_xor(v, 32, 64);
    v += __shfl_xor(v, 16, 64);
    v += __shfl_xor(v, 8, 64);
    v += __shfl_xor(v, 4, 64);
    v += __shfl_xor(v, 2, 64);
    v += __shfl_xor(v, 1, 64);
    wacc[q] = v;
  }
  if (lane == 0) {
    for (int dh = 0; dh < 3; ++dh)
      for (int j = 0; j < 25; ++j) {
        float a = 0.f;
        for (int dw = 0; dw < 3; ++dw) {
          int w = j + 1 - dw;
          if (w >= 0 && w < 25) a += wacc[dh * 3 + dw] * Wconv2[w];
        }
        A[(dh * 25 + j) * 256 + c] = a;
      }
  }
}

// x0T[((b*256+h)*25+w)*256+c] = x0[((b*256+c)*256+h)*25+w]
__global__ __launch_bounds__(256) void k1_transpose(
    const float* __restrict__ in, float* __restrict__ out)
{
  __shared__ float tile[32][33];
  const int nt = blockIdx.x;            // 0..199
  const int ct = blockIdx.y;            // 0..7
  const int b = blockIdx.z;             // 0..7
  const int tx = threadIdx.x & 31, ty = threadIdx.x >> 5;
  const int n = nt * 32 + tx;
#pragma unroll
  for (int r = 0; r < 4; ++r) {
    int c = ct * 32 + ty + r * 8;
    tile[ty + r * 8][tx] = in[(size_t)(b * 256 + c) * 6400 + n];
  }
  __syncthreads();
  const int c2 = ct * 32 + tx;
#pragma unroll
  for (int r = 0; r < 4; ++r) {
    int n2 = nt * 32 + ty + r * 8;
    out[(size_t)(b * 6400 + n2) * 256 + c2] = tile[tx][ty + r * 8];
  }
}

// ---- MFMA dual-recurrence kernel ----
// Block = 512 threads (8 waves). Wave w owns channels [32w, 32w+32) (2 M-tiles).
// Columns: block owns 8 (b,h) columns; lane n=lane&15: n<8 -> y col n, n>=8 -> z col n-8.
// Per step: C = Wc @ [Y_prev | Z_prev]  (M=256,N=16,K=256) via 16 MFMA/wave.
__global__ __launch_bounds__(512) void k2_mfma(
    const float* __restrict__ X,     // x0T [col][w][c]
    const short* __restrict__ WcA,   // bf16 [o][c]
    const float* __restrict__ A,     // [(dh*25+w)*256+c]
    const float* __restrict__ bnp,   // inv[256], add[256]
    float* __restrict__ S)           // [col*3+dh]
{
  __shared__ short yz[2][16 * 256];  // bf16 B-tile [n][c], XOR-swizzled
  __shared__ float red[8][8][3];
  const int tid = threadIdx.x;
  const int wave = tid >> 6;
  const int lane = tid & 63;
  const int n = lane & 15;
  const int g = lane >> 4;
  const bool isz = (n >= 8);
  const int col0 = blockIdx.x * NC;
  const size_t colbase = (size_t)(col0 + (n & 7)) * 6400;
  const int obase = wave * 32;

  // BN params for this lane's 2 tiles x 4 rows (o = obase + t*16 + g*4 + r)
  f32x4 inv[2], addv[2];
#pragma unroll
  for (int t = 0; t < 2; ++t) {
    inv[t] = *(const f32x4*)(bnp + obase + t * 16 + g * 4);
    addv[t] = *(const f32x4*)(bnp + 256 + obase + t * 16 + g * 4);
  }

  // A-operand fragments: Wc rows m = obase + t*16 + (lane&15), k = kk*32 + g*8 + i
  bf16x8 af[2][8];
#pragma unroll
  for (int t = 0; t < 2; ++t)
#pragma unroll
    for (int kk = 0; kk < 8; ++kk)
      af[t][kk] = *(const bf16x8*)(WcA + (obase + t * 16 + n) * 256 + kk * 32 + g * 8);

  // LDS offsets (byte), XOR-swizzle within 512B row to kill 16-way conflicts
  char* smem = (char*)yz;
  const int swz = (n & 7) << 4;
  int woff[2], roff[8];
#pragma unroll
  for (int t = 0; t < 2; ++t)
    woff[t] = n * 512 + (((obase + t * 16 + g * 4) * 2) ^ swz);
#pragma unroll
  for (int kk = 0; kk < 8; ++kk)
    roff[kk] = n * 512 + ((kk * 64 + g * 16) ^ swz);

  float sA0 = 0.f, sA1 = 0.f, sA2 = 0.f;

  // ---- k = 0 ----
  {
    f32x4 a4[3][2];
#pragma unroll
    for (int dh = 0; dh < 3; ++dh)
#pragma unroll
      for (int t = 0; t < 2; ++t) a4[dh][t] = (f32x4){0.f, 0.f, 0.f, 0.f};
    if (isz) {
#pragma unroll
      for (int dh = 0; dh < 3; ++dh)
#pragma unroll
        for (int t = 0; t < 2; ++t)
          a4[dh][t] = *(const f32x4*)(A + (dh * 25 + 24) * 256 + obase + t * 16 + g * 4);
    }
    short vp[2][4];
#pragma unroll
    for (int t = 0; t < 2; ++t) {
      f32x4 x0 = *(const f32x4*)(X + colbase + obase + t * 16 + g * 4);
#pragma unroll
      for (int r = 0; r < 4; ++r) {
        float v = x0[r];
        if (isz) v = relu_(v * inv[t][r] + addv[t][r]);  // z0 = f(y0)
        float t2 = relu_(v * inv[t][r] + addv[t][r]);
        sA0 = fmaf(a4[0][t][r], t2, sA0);
        sA1 = fmaf(a4[1][t][r], t2, sA1);
        sA2 = fmaf(a4[2][t][r], t2, sA2);
        vp[t][r] = f2bf(v);
      }
    }
#pragma unroll
    for (int t = 0; t < 2; ++t)
      *(short4*)(smem + woff[t]) = make_short4(vp[t][0], vp[t][1], vp[t][2], vp[t][3]);
  }
  __syncthreads();

  // ---- steps k = 1..24 ----
#pragma unroll 1
  for (int k = 1; k < 25; ++k) {
    const int cur = (k - 1) & 1, nxt = k & 1;
    const int w = 24 - k;

    // prefetch x (y-lanes only) and A coefficients (z-lanes only)
    f32x4 xk[2];
    xk[0] = (f32x4){0.f, 0.f, 0.f, 0.f};
    xk[1] = (f32x4){0.f, 0.f, 0.f, 0.f};
    if (!isz) {
#pragma unroll
      for (int t = 0; t < 2; ++t)
        xk[t] = *(const f32x4*)(X + colbase + (size_t)k * 256 + obase + t * 16 + g * 4);
    }
    f32x4 a4[3][2];
#pragma unroll
    for (int dh = 0; dh < 3; ++dh)
#pragma unroll
      for (int t = 0; t < 2; ++t) a4[dh][t] = (f32x4){0.f, 0.f, 0.f, 0.f};
    if (isz) {
#pragma unroll
      for (int dh = 0; dh < 3; ++dh)
#pragma unroll
        for (int t = 0; t < 2; ++t)
          a4[dh][t] = *(const f32x4*)(A + (dh * 25 + w) * 256 + obase + t * 16 + g * 4);
    }

    // B fragments from LDS
    bf16x8 b[8];
#pragma unroll
    for (int kk = 0; kk < 8; ++kk)
      b[kk] = *(const bf16x8*)(smem + cur * 8192 + roff[kk]);

    f32x4 acc0 = (f32x4){0.f, 0.f, 0.f, 0.f};
    f32x4 acc1 = (f32x4){0.f, 0.f, 0.f, 0.f};
#pragma unroll
    for (int kk = 0; kk < 8; ++kk) {
      acc0 = __builtin_amdgcn_mfma_f32_16x16x32_bf16(af[0][kk], b[kk], acc0, 0, 0, 0);
      acc1 = __builtin_amdgcn_mfma_f32_16x16x32_bf16(af[1][kk], b[kk], acc1, 0, 0, 0);
    }

    // epilogue: y-lanes form y_new,t1; z-lanes form z_new,t2, accumulate S
    short vp[2][4];
#pragma unroll
    for (int t = 0; t < 2; ++t) {
      f32x4 acc = t ? acc1 : acc0;
#pragma unroll
      for (int r = 0; r < 4; ++r) {
        float cy = relu_(acc[r]);
        float ynew = xk[t][r] + cy;                       // valid on y-lanes
        float t1 = relu_(ynew * inv[t][r] + addv[t][r]);  // valid on y-lanes
        float t1s = __shfl_xor(t1, 8);                    // y -> z partner
        float znew = t1s + cy;                            // valid on z-lanes
        float t2 = relu_(znew * inv[t][r] + addv[t][r]);
        sA0 = fmaf(a4[0][t][r], t2, sA0);
        sA1 = fmaf(a4[1][t][r], t2, sA1);
        sA2 = fmaf(a4[2][t][r], t2, sA2);
        vp[t][r] = f2bf(isz ? znew : ynew);
      }
    }
#pragma unroll
    for (int t = 0; t < 2; ++t)
      *(short4*)(smem + nxt * 8192 + woff[t]) =
          make_short4(vp[t][0], vp[t][1], vp[t][2], vp[t][3]);
    __syncthreads();
  }

  // ---- reduce sA across g-groups and waves -> S[col][dh] ----
  sA0 += __shfl_xor(sA0, 16); sA0 += __shfl_xor(sA0, 32);
  sA1 += __shfl_xor(sA1, 16); sA1 += __shfl_xor(sA1, 32);
  sA2 += __shfl_xor(sA2, 16); sA2 += __shfl_xor(sA2, 32);
  if (isz && g == 0) {
    red[wave][n - 8][0] = sA0;
    red[wave][n - 8][1] = sA1;
    red[wave][n - 8][2] = sA2;
  }
  __syncthreads();
  if (tid < 24) {
    int nn = tid / 3, dh = tid % 3;
    float v = 0.f;
#pragma unroll
    for (int ww = 0; ww < 8; ++ww) v += red[ww][nn][dh];
    S[(size_t)(col0 + nn) * 3 + dh] = v;
  }
}

// ---- fallback VALU kernel (original, used only if ws too small) ----
__global__ __launch_bounds__(256) void k2_scnn_fb(
    const float* __restrict__ X,    // x0 [b][c][h][w]
    const float* __restrict__ WcT,  // [c][o]
    const float* __restrict__ A,
    const float* __restrict__ bnp,
    float* __restrict__ S)
{
  __shared__ float ly[256 * NC];
  __shared__ float lz[256 * NC];
  __shared__ float red[4 * NC * 3];
  const int o = threadIdx.x;
  const int col0 = blockIdx.x * NC;
  const float inv = bnp[o], add = bnp[256 + o];

  float yv[NC], zv[NC], sA0[NC], sA1[NC], sA2[NC];
#pragma unroll
  for (int n = 0; n < NC; ++n) { sA0[n] = 0.f; sA1[n] = 0.f; sA2[n] = 0.f; }

  auto loadx = [&](int n, int w) -> float {
    int b = col0 >> 8, h = (col0 & 255) + n;
    return X[((size_t)(b * 256 + o) * 256 + h) * 25 + w];
  };

#pragma unroll
  for (int n = 0; n < NC; ++n) {
    yv[n] = loadx(n, 0);
    zv[n] = relu_(yv[n] * inv + add);
  }
  {
    const int w = 24;
    float a0 = A[(0 * 25 + w) * 256 + o];
    float a1 = A[(1 * 25 + w) * 256 + o];
    float a2 = A[(2 * 25 + w) * 256 + o];
#pragma unroll
    for (int n = 0; n < NC; ++n) {
      float t2c = relu_(zv[n] * inv + add);
      sA0[n] += a0 * t2c; sA1[n] += a1 * t2c; sA2[n] += a2 * t2c;
    }
  }

  for (int k = 1; k < 25; ++k) {
    float4* lyw = (float4*)ly;
    float4* lzw = (float4*)lz;
    lyw[o * 2]     = make_float4(yv[0], yv[1], yv[2], yv[3]);
    lyw[o * 2 + 1] = make_float4(yv[4], yv[5], yv[6], yv[7]);
    lzw[o * 2]     = make_float4(zv[0], zv[1], zv[2], zv[3]);
    lzw[o * 2 + 1] = make_float4(zv[4], zv[5], zv[6], zv[7]);
    __syncthreads();

    float ay[NC], az[NC];
#pragma unroll
    for (int nn = 0; nn < NC; ++nn) { ay[nn] = 0.f; az[nn] = 0.f; }
    const float4* lyv = (const float4*)ly;
    const float4* lzv = (const float4*)lz;
#pragma unroll 4
    for (int c = 0; c < 256; ++c) {
      float wv = WcT[c * 256 + o];
      float4 ya = lyv[2 * c], yb = lyv[2 * c + 1];
      float4 za = lzv[2 * c], zb = lzv[2 * c + 1];
      ay[0] = fmaf(wv, ya.x, ay[0]); ay[1] = fmaf(wv, ya.y, ay[1]);
      ay[2] = fmaf(wv, ya.z, ay[2]); ay[3] = fmaf(wv, ya.w, ay[3]);
      ay[4] = fmaf(wv, yb.x, ay[4]); ay[5] = fmaf(wv, yb.y, ay[5]);
      ay[6] = fmaf(wv, yb.z, ay[6]); ay[7] = fmaf(wv, yb.w, ay[7]);
      az[0] = fmaf(wv, za.x, az[0]); az[1] = fmaf(wv, za.y, az[1]);
      az[2] = fmaf(wv, za.z, az[2]); az[3] = fmaf(wv, za.w, az[3]);
      az[4] = fmaf(wv, zb.x, az[4]); az[5] = fmaf(wv, zb.y, az[5]);
      az[6] = fmaf(wv, zb.z, az[6]); az[7] = fmaf(wv, zb.w, az[7]);
    }

    const int w = 24 - k;
    float a0 = A[(0 * 25 + w) * 256 + o];
    float a1 = A[(1 * 25 + w) * 256 + o];
    float a2 = A[(2 * 25 + w) * 256 + o];
#pragma unroll
    for (int nn = 0; nn < NC; ++nn) {
      float ynew = loadx(nn, k) + relu_(ay[nn]);
      float t1c = relu_(ynew * inv + add);
      float znew = t1c + relu_(az[nn]);
      float t2c = relu_(znew * inv + add);
      sA0[nn] += a0 * t2c; sA1[nn] += a1 * t2c; sA2[nn] += a2 * t2c;
      yv[nn] = ynew;
      zv[nn] = znew;
    }
    __syncthreads();
  }

  const int lane = o & 63, wid = o >> 6;
#pragma unroll
  for (int nn = 0; nn < NC; ++nn) {
#pragma unroll
    for (int dh = 0; dh < 3; ++dh) {
      float v = (dh == 0) ? sA0[nn] : (dh == 1 ? sA1[nn] : sA2[nn]);
      v += __shfl_xor(v, 32, 64);
      v += __shfl_xor(v, 16, 64);
      v += __shfl_xor(v, 8, 64);
      v += __shfl_xor(v, 4, 64);
      v += __shfl_xor(v, 2, 64);
      v += __shfl_xor(v, 1, 64);
      if (lane == 0) red[wid * (NC * 3) + nn * 3 + dh] = v;
    }
  }
  __syncthreads();
  if (o < NC * 3) {
    float v = red[o] + red[NC * 3 + o] + red[2 * NC * 3 + o] + red[3 * NC * 3 + o];
    int nn = o / 3, dh = o % 3;
    S[(size_t)(col0 + nn) * 3 + dh] = v;
  }
}

// P[b][h'] for h' in [0,512)
__global__ __launch_bounds__(256) void k3_outpre(
    const float* __restrict__ S, float* __restrict__ P)
{
  int idx = blockIdx.x * blockDim.x + threadIdx.x;
  if (idx >= 8 * 512) return;
  int b = idx >> 9, h = idx & 511;
  float acc = 0.f;
#pragma unroll
  for (int dh = 0; dh < 3; ++dh) {
    int hh = h + dh - 1;
    if (hh < 0 || hh >= 512) continue;
    float pos = hh * (255.0f / 511.0f);
    int i0 = (int)floorf(pos);
    int i1 = min(i0 + 1, 255);
    float t = pos - (float)i0;
    acc += (1.f - t) * S[(size_t)(b * 256 + i0) * 3 + dh]
         + t * S[(size_t)(b * 256 + i1) * 3 + dh];
  }
  P[idx] = acc;
}

__global__ __launch_bounds__(256) void k4_final(
    const float* __restrict__ P, float* __restrict__ out)
{
  int idx = blockIdx.x * blockDim.x + threadIdx.x;
  if (idx >= 8 * 2048) return;
  int b = idx >> 11, H = idx & 2047;
  const float* Pb = P + b * 512;

  float pos3 = H * (1023.0f / 2047.0f);
  int i3 = (int)floorf(pos3);
  int i3b = min(i3 + 1, 1023);
  float t3 = pos3 - (float)i3;

  float v[2];
#pragma unroll
  for (int q = 0; q < 2; ++q) {
    int i = q ? i3b : i3;
    float pos2 = i * (511.0f / 1023.0f);
    int i2 = (int)floorf(pos2);
    int i2b = min(i2 + 1, 511);
    float t2 = pos2 - (float)i2;
    v[q] = (1.f - t2) * Pb[i2] + t2 * Pb[i2b];
  }
  float val = (1.f - t3) * v[0] + t3 * v[1];
  out[idx] = 1.f / (1.f + expf(-val));
}

extern "C" void kernel_launch(void* const* d_in, const int* in_sizes, int n_in,
                              void* d_out, int out_size, void* d_ws, size_t ws_size,
                              hipStream_t stream) {
  (void)in_sizes; (void)n_in; (void)out_size;
  const float* p2r    = (const float*)d_in[0];
  const float* Wmsg   = (const float*)d_in[1];
  const float* gamma  = (const float*)d_in[2];
  const float* beta   = (const float*)d_in[3];
  const float* mean   = (const float*)d_in[4];
  const float* var    = (const float*)d_in[5];
  const float* Wup2   = (const float*)d_in[6];
  const float* Wconv  = (const float*)d_in[7];
  const float* Wconv2 = (const float*)d_in[8];
  float* out = (float*)d_out;

  float* ws = (float*)d_ws;
  const size_t X0T_ELEMS = (size_t)8 * 256 * 25 * 256;  // 13,107,200 floats
  const size_t SMALL_ELEMS = 65536 + 32768 + 19200 + 512 + 6144 + 4096 + 64;
  bool use_tr = ws_size >= (X0T_ELEMS + SMALL_ELEMS) * sizeof(float);

  size_t off = 0;
  float* x0T = nullptr;
  if (use_tr) { x0T = ws; off += X0T_ELEMS; }
  float* WcT = ws + off;  off += 65536;
  short* WcA = (short*)(ws + off); off += 32768;  // 65536 bf16
  float* Abuf = ws + off; off += 19200;
  float* bnp = ws + off;  off += 512;
  float* S = ws + off;    off += 6144;
  float* P = ws + off;    off += 4096;

  k0_precompute<<<256, 64, 0, stream>>>(Wmsg, gamma, beta, mean, var, Wup2,
                                        Wconv, Wconv2, WcT, WcA, Abuf, bnp);
  if (use_tr) {
    dim3 tg(200, 8, 8);
    k1_transpose<<<tg, 256, 0, stream>>>(p2r, x0T);
    k2_mfma<<<256, 512, 0, stream>>>(x0T, (const short*)WcA, Abuf, bnp, S);
  } else {
    k2_scnn_fb<<<256, 256, 0, stream>>>(p2r, WcT, Abuf, bnp, S);
  }
  k3_outpre<<<16, 256, 0, stream>>>(S, P);
  k4_final<<<64, 256, 0, stream>>>(P, out);
}

// Round 3
// 60.140 us; speedup vs baseline: 5.8031x; 1.3668x over previous
//
#include <hip/hip_runtime.h>
#include <math.h>

// Algebraic refactor (verified rounds 1-2):
//  y[0]=x[...,0]; y[k]=x[...,k]+relu(Wc@y[k-1])
//  z[0]=f(y[0]);  z[k]=f(y[k])+relu(Wc@z[k-1]),  f(v)=relu(v*inv+add)
//  S[col][dh] = sum_{o,k} A[dh][24-k][o] * f(z[k])[o][col]
//  tail: lerp chains + sigmoid (k3,k4)
// Round 3: fuse the x-transpose INTO k2. Block stages its whole x-slab
//  (8 cols x 25 w x 256 c) coalesced -> bf16 LDS [w][n][c] (swizzled).
//  A is register-prefetched one step ahead. MFMA acc chains split 2x.

#define NC 8

typedef __attribute__((ext_vector_type(8))) short bf16x8;
typedef __attribute__((ext_vector_type(4))) float f32x4;

__device__ __forceinline__ float relu_(float v) { return fmaxf(v, 0.f); }

__device__ __forceinline__ short f2bf(float f) {
  union { float f; unsigned u; } v; v.f = f;
  unsigned r = (v.u + 0x7fffu + ((v.u >> 16) & 1u)) >> 16;
  return (short)r;
}
__device__ __forceinline__ float bf2f(short s) {
  union { unsigned u; float f; } v;
  v.u = ((unsigned)(unsigned short)s) << 16;
  return v.f;
}

__global__ __launch_bounds__(64) void k0_precompute(
    const float* __restrict__ Wmsg, const float* __restrict__ gamma,
    const float* __restrict__ beta, const float* __restrict__ mean,
    const float* __restrict__ var, const float* __restrict__ Wup2,
    const float* __restrict__ Wconv, const float* __restrict__ Wconv2,
    short* __restrict__ WcA, float* __restrict__ A, float* __restrict__ bnp)
{
  const int c = blockIdx.x;      // 0..255
  const int lane = threadIdx.x;  // 0..63

  // WcA[o][c] = bf16(Wc[o][c]) (MFMA A operand, row-major [M=o][K=c])
  for (int o = lane; o < 256; o += 64)
    WcA[o * 256 + c] = f2bf(Wmsg[(o * 256 + c) * 9 + 4]);

  const int gtid = c * 64 + lane;
  if (gtid < 256) {
    float inv = gamma[gtid] / sqrtf(var[gtid] + 1e-5f);
    bnp[gtid] = inv;
    bnp[256 + gtid] = beta[gtid] - mean[gtid] * inv;
  }

  float wacc[9];
#pragma unroll
  for (int q = 0; q < 9; ++q) wacc[q] = 0.f;
  for (int o = lane; o < 256; o += 64) {
    float cw = Wconv[o];
    const float* wp = Wup2 + (size_t)(o * 256 + c) * 9;
#pragma unroll
    for (int q = 0; q < 9; ++q) wacc[q] += cw * wp[q];
  }
#pragma unroll
  for (int q = 0; q < 9; ++q) {
    float v = wacc[q];
    v += __shfl_xor(v, 32, 64);
    v += __shfl_xor(v, 16, 64);
    v += __shfl_xor(v, 8, 64);
    v += __shfl_xor(v, 4, 64);
    v += __shfl_xor(v, 2, 64);
    v += __shfl_xor(v, 1, 64);
    wacc[q] = v;
  }
  if (lane == 0) {
    for (int dh = 0; dh < 3; ++dh)
      for (int j = 0; j < 25; ++j) {
        float a = 0.f;
        for (int dw = 0; dw < 3; ++dw) {
          int w = j + 1 - dw;
          if (w >= 0 && w < 25) a += wacc[dh * 3 + dw] * Wconv2[w];
        }
        A[(dh * 25 + j) * 256 + c] = a;
      }
  }
}

// ---- fused MFMA dual-recurrence kernel ----
// Block = 512 threads (8 waves). Wave w owns channels [32w, 32w+32).
// lane n=lane&15: n<8 -> y col n, n>=8 -> z col n-8 (cols = 8 consecutive h).
// Per step: C = Wc @ [Y_prev | Z_prev]  (M=256,N=16,K=256), 16 MFMA/wave.
__global__ __launch_bounds__(512) void k2_fused(
    const float* __restrict__ X,     // original p2_r [b][c][h][w]
    const short* __restrict__ WcA,   // bf16 [o][c]
    const float* __restrict__ A,     // [(dh*25+w)*256+c]
    const float* __restrict__ bnp,   // inv[256], add[256]
    float* __restrict__ S)           // [col*3+dh]
{
  __shared__ short xslab[25 * 8 * 256];  // bf16 x [w][n][c], swizzled (102400B)
  __shared__ short yz[2][16 * 256];      // bf16 state [n][c], swizzled (2x8192B)
  __shared__ float red[8][8][3];
  const int tid = threadIdx.x;
  const int wave = tid >> 6;
  const int lane = tid & 63;
  const int n = lane & 15;
  const int nr = n & 7;
  const int g = lane >> 4;
  const bool isz = (n >= 8);
  const int col0 = blockIdx.x * NC;      // col = b*256+h
  const int b = col0 >> 8, h0 = col0 & 255;
  const int obase = wave * 32;
  char* xs = (char*)xslab;
  char* smem = (char*)yz;

  // ---- stage x-slab: per c, 200 contiguous floats cover (all n, all w) ----
  {
    const int c = tid >> 1;
    const int half = tid & 1;
    const float* src = X + ((size_t)(b * 256 + c) * 256 + h0) * 25 + half * 100;
#pragma unroll
    for (int j = 0; j < 25; ++j) {
      float4 v = *(const float4*)(src + j * 4);
      int f0 = half * 100 + j * 4;
      float vv[4] = {v.x, v.y, v.z, v.w};
#pragma unroll
      for (int e = 0; e < 4; ++e) {
        int f = f0 + e;
        int rn = f / 25;
        int w = f - rn * 25;
        *(short*)(xs + w * 4096 + rn * 512 + ((2 * c) ^ (rn << 4))) = f2bf(vv[e]);
      }
    }
  }

  // BN params: o = obase + t*16 + g*4 + r
  f32x4 inv[2], addv[2];
#pragma unroll
  for (int t = 0; t < 2; ++t) {
    inv[t] = *(const f32x4*)(bnp + obase + t * 16 + g * 4);
    addv[t] = *(const f32x4*)(bnp + 256 + obase + t * 16 + g * 4);
  }

  // A-operand fragments: rows m = obase + t*16 + n, k = kk*32 + g*8 + i
  bf16x8 af[2][8];
#pragma unroll
  for (int t = 0; t < 2; ++t)
#pragma unroll
    for (int kk = 0; kk < 8; ++kk)
      af[t][kk] = *(const bf16x8*)(WcA + (obase + t * 16 + n) * 256 + kk * 32 + g * 8);

  // LDS byte offsets, XOR-swizzled
  const int swz = nr << 4;
  int woff[2], roff[8], xoff[2];
#pragma unroll
  for (int t = 0; t < 2; ++t) {
    woff[t] = n * 512 + (((obase + t * 16 + g * 4) * 2) ^ swz);
    xoff[t] = nr * 512 + (((obase + t * 16 + g * 4) * 2) ^ swz);
  }
#pragma unroll
  for (int kk = 0; kk < 8; ++kk)
    roff[kk] = n * 512 + ((kk * 64 + g * 16) ^ swz);

  float sA0 = 0.f, sA1 = 0.f, sA2 = 0.f;

  __syncthreads();  // slab ready

  // ---- k = 0 ----
  {
    f32x4 a4[3][2];
#pragma unroll
    for (int dh = 0; dh < 3; ++dh)
#pragma unroll
      for (int t = 0; t < 2; ++t) a4[dh][t] = (f32x4){0.f, 0.f, 0.f, 0.f};
    if (isz) {
#pragma unroll
      for (int dh = 0; dh < 3; ++dh)
#pragma unroll
        for (int t = 0; t < 2; ++t)
          a4[dh][t] = *(const f32x4*)(A + (dh * 25 + 24) * 256 + obase + t * 16 + g * 4);
    }
    short vp[2][4];
#pragma unroll
    for (int t = 0; t < 2; ++t) {
      uint2 q = *(const uint2*)(xs + xoff[t]);  // w = 0 plane
      short xb[4] = {(short)(q.x), (short)(q.x >> 16), (short)(q.y), (short)(q.y >> 16)};
#pragma unroll
      for (int r = 0; r < 4; ++r) {
        float v = bf2f(xb[r]);
        if (isz) v = relu_(v * inv[t][r] + addv[t][r]);  // z0 = f(y0)
        float t2 = relu_(v * inv[t][r] + addv[t][r]);
        sA0 = fmaf(a4[0][t][r], t2, sA0);
        sA1 = fmaf(a4[1][t][r], t2, sA1);
        sA2 = fmaf(a4[2][t][r], t2, sA2);
        vp[t][r] = f2bf(v);
      }
    }
#pragma unroll
    for (int t = 0; t < 2; ++t)
      *(short4*)(smem + woff[t]) = make_short4(vp[t][0], vp[t][1], vp[t][2], vp[t][3]);
  }

  // prefetch A for k=1 (w=23)
  f32x4 aN[3][2];
#pragma unroll
  for (int dh = 0; dh < 3; ++dh)
#pragma unroll
    for (int t = 0; t < 2; ++t) aN[dh][t] = (f32x4){0.f, 0.f, 0.f, 0.f};
  if (isz) {
#pragma unroll
    for (int dh = 0; dh < 3; ++dh)
#pragma unroll
      for (int t = 0; t < 2; ++t)
        aN[dh][t] = *(const f32x4*)(A + (dh * 25 + 23) * 256 + obase + t * 16 + g * 4);
  }
  __syncthreads();

  // ---- steps k = 1..24 ----
#pragma unroll 1
  for (int k = 1; k < 25; ++k) {
    const int cur = (k - 1) & 1, nxt = k & 1;

    // LDS reads: B fragments + this step's x quads
    bf16x8 bfr[8];
#pragma unroll
    for (int kk = 0; kk < 8; ++kk)
      bfr[kk] = *(const bf16x8*)(smem + cur * 8192 + roff[kk]);
    uint2 xq[2];
    xq[0] = make_uint2(0u, 0u);
    xq[1] = make_uint2(0u, 0u);
    if (!isz) {
#pragma unroll
      for (int t = 0; t < 2; ++t)
        xq[t] = *(const uint2*)(xs + k * 4096 + xoff[t]);
    }

    // rotate A, issue next prefetch
    f32x4 aC[3][2];
#pragma unroll
    for (int dh = 0; dh < 3; ++dh)
#pragma unroll
      for (int t = 0; t < 2; ++t) aC[dh][t] = aN[dh][t];
    if (isz && k < 24) {
      const int wn = 23 - k;
#pragma unroll
      for (int dh = 0; dh < 3; ++dh)
#pragma unroll
        for (int t = 0; t < 2; ++t)
          aN[dh][t] = *(const f32x4*)(A + (dh * 25 + wn) * 256 + obase + t * 16 + g * 4);
    }

    // MFMA: split chains
    f32x4 acc0a = (f32x4){0.f, 0.f, 0.f, 0.f};
    f32x4 acc0b = (f32x4){0.f, 0.f, 0.f, 0.f};
    f32x4 acc1a = (f32x4){0.f, 0.f, 0.f, 0.f};
    f32x4 acc1b = (f32x4){0.f, 0.f, 0.f, 0.f};
#pragma unroll
    for (int kk = 0; kk < 4; ++kk) {
      acc0a = __builtin_amdgcn_mfma_f32_16x16x32_bf16(af[0][kk], bfr[kk], acc0a, 0, 0, 0);
      acc1a = __builtin_amdgcn_mfma_f32_16x16x32_bf16(af[1][kk], bfr[kk], acc1a, 0, 0, 0);
    }
#pragma unroll
    for (int kk = 4; kk < 8; ++kk) {
      acc0b = __builtin_amdgcn_mfma_f32_16x16x32_bf16(af[0][kk], bfr[kk], acc0b, 0, 0, 0);
      acc1b = __builtin_amdgcn_mfma_f32_16x16x32_bf16(af[1][kk], bfr[kk], acc1b, 0, 0, 0);
    }
    f32x4 acc0 = acc0a + acc0b;
    f32x4 acc1 = acc1a + acc1b;

    // epilogue
    short vp[2][4];
#pragma unroll
    for (int t = 0; t < 2; ++t) {
      f32x4 acc = t ? acc1 : acc0;
      short xb[4] = {(short)(xq[t].x), (short)(xq[t].x >> 16),
                     (short)(xq[t].y), (short)(xq[t].y >> 16)};
#pragma unroll
      for (int r = 0; r < 4; ++r) {
        float cy = relu_(acc[r]);
        float ynew = bf2f(xb[r]) + cy;                    // valid on y-lanes
        float t1 = relu_(ynew * inv[t][r] + addv[t][r]);  // valid on y-lanes
        float t1s = __shfl_xor(t1, 8);                    // y -> z partner
        float znew = t1s + cy;                            // valid on z-lanes
        float t2 = relu_(znew * inv[t][r] + addv[t][r]);
        sA0 = fmaf(aC[0][t][r], t2, sA0);
        sA1 = fmaf(aC[1][t][r], t2, sA1);
        sA2 = fmaf(aC[2][t][r], t2, sA2);
        vp[t][r] = f2bf(isz ? znew : ynew);
      }
    }
#pragma unroll
    for (int t = 0; t < 2; ++t)
      *(short4*)(smem + nxt * 8192 + woff[t]) =
          make_short4(vp[t][0], vp[t][1], vp[t][2], vp[t][3]);
    __syncthreads();
  }

  // ---- reduce sA across g-groups and waves -> S[col][dh] ----
  sA0 += __shfl_xor(sA0, 16); sA0 += __shfl_xor(sA0, 32);
  sA1 += __shfl_xor(sA1, 16); sA1 += __shfl_xor(sA1, 32);
  sA2 += __shfl_xor(sA2, 16); sA2 += __shfl_xor(sA2, 32);
  if (isz && g == 0) {
    red[wave][n - 8][0] = sA0;
    red[wave][n - 8][1] = sA1;
    red[wave][n - 8][2] = sA2;
  }
  __syncthreads();
  if (tid < 24) {
    int nn = tid / 3, dh = tid % 3;
    float v = 0.f;
#pragma unroll
    for (int ww = 0; ww < 8; ++ww) v += red[ww][nn][dh];
    S[(size_t)(col0 + nn) * 3 + dh] = v;
  }
}

// P[b][h'] for h' in [0,512)
__global__ __launch_bounds__(256) void k3_outpre(
    const float* __restrict__ S, float* __restrict__ P)
{
  int idx = blockIdx.x * blockDim.x + threadIdx.x;
  if (idx >= 8 * 512) return;
  int b = idx >> 9, h = idx & 511;
  float acc = 0.f;
#pragma unroll
  for (int dh = 0; dh < 3; ++dh) {
    int hh = h + dh - 1;
    if (hh < 0 || hh >= 512) continue;
    float pos = hh * (255.0f / 511.0f);
    int i0 = (int)floorf(pos);
    int i1 = min(i0 + 1, 255);
    float t = pos - (float)i0;
    acc += (1.f - t) * S[(size_t)(b * 256 + i0) * 3 + dh]
         + t * S[(size_t)(b * 256 + i1) * 3 + dh];
  }
  P[idx] = acc;
}

__global__ __launch_bounds__(256) void k4_final(
    const float* __restrict__ P, float* __restrict__ out)
{
  int idx = blockIdx.x * blockDim.x + threadIdx.x;
  if (idx >= 8 * 2048) return;
  int b = idx >> 11, H = idx & 2047;
  const float* Pb = P + b * 512;

  float pos3 = H * (1023.0f / 2047.0f);
  int i3 = (int)floorf(pos3);
  int i3b = min(i3 + 1, 1023);
  float t3 = pos3 - (float)i3;

  float v[2];
#pragma unroll
  for (int q = 0; q < 2; ++q) {
    int i = q ? i3b : i3;
    float pos2 = i * (511.0f / 1023.0f);
    int i2 = (int)floorf(pos2);
    int i2b = min(i2 + 1, 511);
    float t2 = pos2 - (float)i2;
    v[q] = (1.f - t2) * Pb[i2] + t2 * Pb[i2b];
  }
  float val = (1.f - t3) * v[0] + t3 * v[1];
  out[idx] = 1.f / (1.f + expf(-val));
}

extern "C" void kernel_launch(void* const* d_in, const int* in_sizes, int n_in,
                              void* d_out, int out_size, void* d_ws, size_t ws_size,
                              hipStream_t stream) {
  (void)in_sizes; (void)n_in; (void)out_size; (void)ws_size;
  const float* p2r    = (const float*)d_in[0];
  const float* Wmsg   = (const float*)d_in[1];
  const float* gamma  = (const float*)d_in[2];
  const float* beta   = (const float*)d_in[3];
  const float* mean   = (const float*)d_in[4];
  const float* var    = (const float*)d_in[5];
  const float* Wup2   = (const float*)d_in[6];
  const float* Wconv  = (const float*)d_in[7];
  const float* Wconv2 = (const float*)d_in[8];
  float* out = (float*)d_out;

  float* ws = (float*)d_ws;
  size_t off = 0;
  short* WcA = (short*)(ws + off); off += 32768;  // 65536 bf16
  float* Abuf = ws + off; off += 19200;
  float* bnp = ws + off;  off += 512;
  float* S = ws + off;    off += 6144;
  float* P = ws + off;    off += 4096;

  k0_precompute<<<256, 64, 0, stream>>>(Wmsg, gamma, beta, mean, var, Wup2,
                                        Wconv, Wconv2, WcA, Abuf, bnp);
  k2_fused<<<256, 512, 0, stream>>>(p2r, (const short*)WcA, Abuf, bnp, S);
  k3_outpre<<<16, 256, 0, stream>>>(S, P);
  k4_final<<<64, 256, 0, stream>>>(P, out);
}